// Round 2
// baseline (1269.936 us; speedup 1.0000x reference)
//
#include <hip/hip_runtime.h>
#include <hip/hip_bf16.h>

#define NN 100000
#define NEG 1600000
#define DD 256
#define DOUT 128

typedef unsigned short u16;
typedef unsigned int u32;
typedef __attribute__((ext_vector_type(8))) __bf16 bf16x8;
typedef __attribute__((ext_vector_type(4))) float f32x4;

__device__ __forceinline__ float b2f(u16 b){ u32 u=((u32)b)<<16; float f; __builtin_memcpy(&f,&u,4); return f; }
__device__ __forceinline__ u16 f2b(float f){ u32 u; __builtin_memcpy(&u,&f,4); u32 r=(u + 0x7FFFu + ((u>>16)&1u))>>16; return (u16)r; }
__device__ __forceinline__ u32 pack2(float a, float b){ return (u32)f2b(a) | ((u32)f2b(b)<<16); }

// async 16B global -> LDS (lane i lands at ldsbase + i*16)
__device__ __forceinline__ void cp16(const u16* g, u16* l){
  __builtin_amdgcn_global_load_lds((const __attribute__((address_space(1))) u16*)g,
                                   (__attribute__((address_space(3))) u16*)l, 16, 0, 0);
}

// ---------------- x fp32 -> bf16 ----------------
__global__ void k_cvt(const float* __restrict__ x, u16* __restrict__ xb){
  size_t i = (size_t)(blockIdx.x*256 + threadIdx.x)*8;
  if(i >= (size_t)NN*DD) return;
  float4 a = *(const float4*)&x[i];
  float4 b = *(const float4*)&x[i+4];
  uint4 v; v.x=pack2(a.x,a.y); v.y=pack2(a.z,a.w); v.z=pack2(b.x,b.y); v.w=pack2(b.z,b.w);
  *(uint4*)&xb[i] = v;
}

// ---------------- weight transpose (fp32 [256][ncols] -> bf16 [ncols][256]) ----------------
__global__ void k_wtrans(const float* __restrict__ W, u16* __restrict__ WT, int ncols){
  int n = blockIdx.x; int k = threadIdx.x;
  WT[n*DD + k] = f2b(W[k*ncols + n]);
}

// ---------------- graph prep ----------------
__global__ void k_deg(const int* __restrict__ ei, int* __restrict__ deg){
  int e = blockIdx.x*256 + threadIdx.x;
  if(e < NEG) atomicAdd(&deg[ei[NEG + e]], 1);
}

__global__ void k_scan_a(const int* __restrict__ deg, int* __restrict__ part){
  __shared__ int s[256];
  int i = blockIdx.x*256 + threadIdx.x;
  int v = (i < NN) ? deg[i] : 0;
  s[threadIdx.x] = v; __syncthreads();
  for(int o=128;o>0;o>>=1){ if(threadIdx.x<o) s[threadIdx.x]+=s[threadIdx.x+o]; __syncthreads(); }
  if(threadIdx.x==0) part[blockIdx.x]=s[0];
}

__global__ void k_scan_b(int* __restrict__ part){
  __shared__ int s[512];
  int tx = threadIdx.x;
  int v = (tx < 391) ? part[tx] : 0;
  s[tx] = v; __syncthreads();
  for(int o=1;o<512;o<<=1){ int t=(tx>=o)?s[tx-o]:0; __syncthreads(); s[tx]+=t; __syncthreads(); }
  if(tx < 391) part[tx] = s[tx]-v;  // exclusive
}

__global__ void k_scan_c(const int* __restrict__ deg, const int* __restrict__ part,
                         int* __restrict__ rowstart, int* __restrict__ cursor, float* __restrict__ dsq){
  __shared__ int s[256];
  int tx = threadIdx.x;
  int i = blockIdx.x*256 + tx;
  int v = (i < NN) ? deg[i] : 0;
  s[tx]=v; __syncthreads();
  for(int o=1;o<256;o<<=1){ int t=(tx>=o)?s[tx-o]:0; __syncthreads(); s[tx]+=t; __syncthreads(); }
  int incl = s[tx];
  int base = part[blockIdx.x];
  if(i < NN){
    int excl = base + incl - v;
    rowstart[i]=excl; cursor[i]=excl;
    dsq[i] = (v>0) ? rsqrtf((float)v) : 0.f;
    if(i == NN-1) rowstart[NN] = base + incl;
  }
}

__global__ void k_csr(const int* __restrict__ ei, int* __restrict__ cursor, int* __restrict__ csr_row){
  int e = blockIdx.x*256 + threadIdx.x;
  if(e < NEG){
    int r = ei[e], c = ei[NEG + e];
    int p = atomicAdd(&cursor[c], 1);
    csr_row[p] = r;
  }
}

// ---------------- BN helpers ----------------
__global__ void k_bnprep(const float* __restrict__ cs, const float* __restrict__ cq,
                         const float* __restrict__ g, const float* __restrict__ b,
                         float* __restrict__ scale, float* __restrict__ shift){
  int c = threadIdx.x;
  float m = cs[c] * (1.0f/NN);
  float var = cq[c] * (1.0f/NN) - m*m;
  float rs = rsqrtf(var + 1e-5f);
  float sc = g[c]*rs;
  scale[c] = sc; shift[c] = b[c] - m*sc;
}

__global__ void k_bnrelu(const u16* __restrict__ yg, const float* __restrict__ scale,
                         const float* __restrict__ shift, u16* __restrict__ g0){
  long long i = (long long)(blockIdx.x*256 + threadIdx.x) * 8;
  if(i >= (long long)NN*DD) return;
  int c0 = (int)(i & 255);
  uint4 v = *(const uint4*)&yg[i];
  const u16* p = (const u16*)&v;
  u32 w[4];
  #pragma unroll
  for(int j=0;j<4;j++){
    float a = fmaxf(b2f(p[2*j  ])*scale[c0+2*j  ]+shift[c0+2*j  ], 0.f);
    float b_ = fmaxf(b2f(p[2*j+1])*scale[c0+2*j+1]+shift[c0+2*j+1], 0.f);
    w[j] = pack2(a,b_);
  }
  uint4 sv; sv.x=w[0]; sv.y=w[1]; sv.z=w[2]; sv.w=w[3];
  *(uint4*)&g0[i] = sv;
}

// ---------------- CSR gather: agg[i] = sum_e dsq[i]*dsq[row]*g0[row] ----------------
__global__ __launch_bounds__(256) void k_gather(const u16* __restrict__ g0, const int* __restrict__ rowstart,
                                                const int* __restrict__ csr_row, const float* __restrict__ dsq,
                                                u16* __restrict__ agg){
  int node = blockIdx.x*8 + (threadIdx.x>>5);
  int lane = threadIdx.x & 31;
  if(node >= NN) return;
  int s = rowstart[node], e = rowstart[node+1];
  float di = dsq[node];
  int d0 = lane*8;
  float acc[8] = {0,0,0,0,0,0,0,0};
  int j = s;
  for(; j+1 < e; j += 2){
    int r0 = csr_row[j], r1 = csr_row[j+1];
    float w0 = di*dsq[r0], w1 = di*dsq[r1];
    uint4 a = *(const uint4*)&g0[(size_t)r0*DD + d0];
    uint4 b = *(const uint4*)&g0[(size_t)r1*DD + d0];
    const u16* pa = (const u16*)&a; const u16* pb = (const u16*)&b;
    #pragma unroll
    for(int t=0;t<8;t++){ acc[t] += w0*b2f(pa[t]); acc[t] += w1*b2f(pb[t]); }
  }
  if(j < e){
    int r0 = csr_row[j]; float w0 = di*dsq[r0];
    uint4 a = *(const uint4*)&g0[(size_t)r0*DD + d0];
    const u16* pa = (const u16*)&a;
    #pragma unroll
    for(int t=0;t<8;t++) acc[t] += w0*b2f(pa[t]);
  }
  u32 w[4];
  #pragma unroll
  for(int t=0;t<4;t++) w[t] = pack2(acc[2*t], acc[2*t+1]);
  uint4 sv; sv.x=w[0]; sv.y=w[1]; sv.z=w[2]; sv.w=w[3];
  *(uint4*)&agg[(size_t)node*DD + d0] = sv;
}

// ---------------- async double-buffered MFMA GEMM ----------------
// EP: 0=LN+relu(h) 1=row-L2-norm(q) 2=rownorm+transp+colsum(kT) 3=transp+colsum(vT)
//     4=store+colstats 5=attention+LN+relu+final-combine->z 6=plain fp32 out 7=split-K atomic (kvs)
enum { EP_LN=0, EP_QN=1, EP_KT=2, EP_VT=3, EP_CS=4, EP_AT=5, EP_PL=6, EP_KV=7 };

template<int EP, int NCOLS>
__global__ __launch_bounds__(256,3)
void k_gemm(const u16* __restrict__ A, const u16* __restrict__ BT,
            const float* __restrict__ bias,
            u16* __restrict__ outb, float* __restrict__ outf,
            const float* __restrict__ p0, const float* __restrict__ p1,
            const float* __restrict__ p2, const float* __restrict__ p3,
            const float* __restrict__ p4, const float* __restrict__ p5,
            const u16* __restrict__ aux0, const u16* __restrict__ aux1, const u16* __restrict__ aux2,
            float* __restrict__ st0, float* __restrict__ st1,
            const u16* __restrict__ zp,
            int kSteps, int kLimit, int Astride, int Bstride, int Mlim)
{
  constexpr int NT = NCOLS/64;
  constexpr int LOGN = (NCOLS==256)?8:7;
  constexpr int TSR = (EP==EP_KT||EP==EP_VT) ? 64 : 1;
  const int tid = threadIdx.x;
  const int wave = tid>>6, lane = tid&63, quad = lane>>4, l15 = lane&15;
  const int m0 = blockIdx.x*64;
  const int kBase = blockIdx.y*(kSteps*32);
  const int wb = wave*(NCOLS/4);

  // kseg-major, lane-contiguous layout: chunk index = kseg*ROWS + row, each chunk 16B
  __shared__ __align__(16) u16 As[2][4*64*8];
  __shared__ __align__(16) u16 Bs[2][4*NCOLS*8];
  __shared__ u16 Ts[TSR][DD+2];
  __shared__ float red[2][4][64];
  __shared__ float dls[64];

  const bool rowok = (m0 + lane) < Mlim;
  const u16* aRow = A + (size_t)(m0 + lane)*Astride + wave*8;   // + k0 at use
  // B: thread handles chunks c = it*256 + tid ; kseg = c>>LOGN (wave-uniform), col = c&(NCOLS-1)
  auto stage = [&](int b, int k0){
    {
      int gk = k0 + wave*8;
      const u16* g = (rowok && gk < kLimit) ? (aRow + k0) : zp;
      cp16(g, &As[b][tid*8]);
    }
    #pragma unroll
    for(int it=0; it<(4*NCOLS)/256; it++){
      int c = it*256 + tid;
      int kseg = c >> LOGN, col = c & (NCOLS-1);
      int gk = k0 + kseg*8;
      const u16* g = (gk < kLimit) ? (BT + (size_t)col*Bstride + gk) : zp;
      cp16(g, &Bs[b][c*8]);
    }
  };

  f32x4 acc[4][NT];
  #pragma unroll
  for(int i=0;i<4;i++)
    #pragma unroll
    for(int j=0;j<NT;j++){ acc[i][j][0]=0.f; acc[i][j][1]=0.f; acc[i][j][2]=0.f; acc[i][j][3]=0.f; }
  float dot[4] = {0.f,0.f,0.f,0.f};

  stage(0, kBase);
  for(int st=0; st<kSteps; st++){
    __syncthreads();               // buf[st&1] complete; prior ds_reads done
    if(st+1 < kSteps) stage((st+1)&1, kBase + (st+1)*32);
    const int cur = st&1;
    uint4 afu[4]; uint4 bfu[NT];
    #pragma unroll
    for(int mi=0;mi<4;mi++) afu[mi] = *(const uint4*)&As[cur][(quad*64 + mi*16 + l15)*8];
    #pragma unroll
    for(int ni=0;ni<NT;ni++) bfu[ni] = *(const uint4*)&Bs[cur][(quad*NCOLS + wb + ni*16 + l15)*8];
    if constexpr (EP==EP_AT){
      const int k0 = kBase + st*32;
      #pragma unroll
      for(int mi=0;mi<4;mi++){
        const u16* ap = (const u16*)&afu[mi];
        #pragma unroll
        for(int j=0;j<8;j++) dot[mi] += b2f(ap[j]) * p2[k0 + quad*8 + j];
      }
    }
    #pragma unroll
    for(int mi=0;mi<4;mi++)
      #pragma unroll
      for(int ni=0;ni<NT;ni++)
        acc[mi][ni] = __builtin_amdgcn_mfma_f32_16x16x32_bf16(
            __builtin_bit_cast(bf16x8, afu[mi]),
            __builtin_bit_cast(bf16x8, bfu[ni]),
            acc[mi][ni], 0,0,0);
  }

  int colg[NT]; float bv[NT];
  #pragma unroll
  for(int ni=0;ni<NT;ni++){ colg[ni] = wb + ni*16 + l15; bv[ni] = bias ? bias[colg[ni]] : 0.f; }

  if constexpr (EP==EP_KV){
    #pragma unroll
    for(int mi=0;mi<4;mi++)
      #pragma unroll
      for(int r=0;r<4;r++){
        int gr = m0 + mi*16 + quad*4 + r;
        if(gr<Mlim){
          #pragma unroll
          for(int ni=0;ni<NT;ni++) atomicAdd(&outf[(size_t)gr*DD + colg[ni]], acc[mi][ni][r]);
        }
      }
    return;
  }
  if constexpr (EP==EP_PL){
    #pragma unroll
    for(int mi=0;mi<4;mi++)
      #pragma unroll
      for(int r=0;r<4;r++){
        int gr = m0 + mi*16 + quad*4 + r;
        if(gr<Mlim){
          #pragma unroll
          for(int ni=0;ni<NT;ni++) outf[(size_t)gr*NCOLS + colg[ni]] = acc[mi][ni][r] + bv[ni];
        }
      }
    return;
  }
  if constexpr (EP==EP_CS){
    float cs[NT], cq[NT];
    #pragma unroll
    for(int ni=0;ni<NT;ni++){ cs[ni]=0.f; cq[ni]=0.f; }
    #pragma unroll
    for(int mi=0;mi<4;mi++)
      #pragma unroll
      for(int r=0;r<4;r++){
        int gr = m0 + mi*16 + quad*4 + r;
        if(gr<Mlim){
          #pragma unroll
          for(int ni=0;ni<NT;ni++){
            float v = acc[mi][ni][r] + bv[ni];
            outb[(size_t)gr*DD + colg[ni]] = f2b(v);
            cs[ni]+=v; cq[ni]+=v*v;
          }
        }
      }
    #pragma unroll
    for(int ni=0;ni<NT;ni++){
      float c=cs[ni], q=cq[ni];
      c += __shfl_xor(c,16); c += __shfl_xor(c,32);
      q += __shfl_xor(q,16); q += __shfl_xor(q,32);
      if(quad==0){ atomicAdd(&st0[colg[ni]], c); atomicAdd(&st1[colg[ni]], q); }
    }
    return;
  }
  if constexpr (EP==EP_QN || EP==EP_KT || EP==EP_VT){
    float rsr[4][4];
    if constexpr (EP!=EP_VT){
      #pragma unroll
      for(int mi=0;mi<4;mi++)
        #pragma unroll
        for(int r=0;r<4;r++){
          float s2=0.f;
          #pragma unroll
          for(int ni=0;ni<NT;ni++){ float v=acc[mi][ni][r]+bv[ni]; s2+=v*v; }
          for(int o=1;o<16;o<<=1) s2 += __shfl_xor(s2,o);
          if(l15==0) red[0][wave][mi*16+quad*4+r] = s2;
        }
      __syncthreads();
      #pragma unroll
      for(int mi=0;mi<4;mi++)
        #pragma unroll
        for(int r=0;r<4;r++){
          int row = mi*16+quad*4+r;
          float S2 = red[0][0][row]+red[0][1][row]+red[0][2][row]+red[0][3][row];
          rsr[mi][r] = rsqrtf(S2);
        }
    } else {
      #pragma unroll
      for(int mi=0;mi<4;mi++)
        #pragma unroll
        for(int r=0;r<4;r++) rsr[mi][r]=1.f;
    }
    if constexpr (EP==EP_QN){
      #pragma unroll
      for(int mi=0;mi<4;mi++)
        #pragma unroll
        for(int r=0;r<4;r++){
          int gr = m0 + mi*16+quad*4+r;
          if(gr<Mlim){
            #pragma unroll
            for(int ni=0;ni<NT;ni++)
              outb[(size_t)gr*DD + colg[ni]] = f2b((acc[mi][ni][r]+bv[ni])*rsr[mi][r]);
          }
        }
      return;
    } else {
      float cs[NT];
      #pragma unroll
      for(int ni=0;ni<NT;ni++) cs[ni]=0.f;
      #pragma unroll
      for(int mi=0;mi<4;mi++)
        #pragma unroll
        for(int r=0;r<4;r++){
          int row = mi*16+quad*4+r;
          int gr = m0 + row;
          #pragma unroll
          for(int ni=0;ni<NT;ni++){
            float v = (gr<Mlim) ? (acc[mi][ni][r]+bv[ni])*rsr[mi][r] : 0.f;
            cs[ni] += v;
            Ts[row][colg[ni]] = f2b(v);
          }
        }
      #pragma unroll
      for(int ni=0;ni<NT;ni++){
        float c=cs[ni];
        c += __shfl_xor(c,16); c += __shfl_xor(c,32);
        if(quad==0) atomicAdd(&st0[colg[ni]], c);
      }
      __syncthreads();
      for(int dd=0;dd<64;dd++){
        int d = wb + dd;
        int gn = m0 + lane;
        if(gn<Mlim) outb[(size_t)d*NN + gn] = Ts[lane][d];
      }
      return;
    }
  }
  if constexpr (EP==EP_AT){
    #pragma unroll
    for(int mi=0;mi<4;mi++){
      float ds = dot[mi];
      ds += __shfl_xor(ds,16); ds += __shfl_xor(ds,32);
      if(wave==0) dls[mi*16+l15] = ds + 200000.0f;   // + 2*nf
    }
    __syncthreads();
    float vs[NT];
    #pragma unroll
    for(int ni=0;ni<NT;ni++) vs[ni] = p3[colg[ni]];
    #pragma unroll
    for(int mi=0;mi<4;mi++)
      #pragma unroll
      for(int r=0;r<4;r++){
        int row = mi*16+quad*4+r;
        int gr = m0 + row;
        float den = dls[row];
        #pragma unroll
        for(int ni=0;ni<NT;ni++){
          float num = acc[mi][ni][r] + 100000.0f*vs[ni];
          float hv = (gr<Mlim) ? b2f(aux0[(size_t)gr*DD + colg[ni]]) : 0.f;
          acc[mi][ni][r] = (num/den + hv)*0.5f;
        }
      }
  }
  if constexpr (EP==EP_LN || EP==EP_AT){
    #pragma unroll
    for(int mi=0;mi<4;mi++)
      #pragma unroll
      for(int r=0;r<4;r++){
        float s=0.f, s2=0.f;
        #pragma unroll
        for(int ni=0;ni<NT;ni++){ float v=acc[mi][ni][r]+bv[ni]; s+=v; s2+=v*v; }
        for(int o=1;o<16;o<<=1){ s += __shfl_xor(s,o); s2 += __shfl_xor(s2,o); }
        if(l15==0){ int row=mi*16+quad*4+r; red[0][wave][row]=s; red[1][wave][row]=s2; }
      }
    __syncthreads();
    float gcol[NT], bcol[NT], p4c[NT], p5c[NT];
    #pragma unroll
    for(int ni=0;ni<NT;ni++){
      gcol[ni]=p0[colg[ni]]; bcol[ni]=p1[colg[ni]];
      if constexpr (EP==EP_AT){ p4c[ni]=p4[colg[ni]]; p5c[ni]=p5[colg[ni]]; }
    }
    #pragma unroll
    for(int mi=0;mi<4;mi++)
      #pragma unroll
      for(int r=0;r<4;r++){
        int row = mi*16+quad*4+r;
        int gr = m0 + row;
        if(gr<Mlim){
          float S  = red[0][0][row]+red[0][1][row]+red[0][2][row]+red[0][3][row];
          float S2 = red[1][0][row]+red[1][1][row]+red[1][2][row]+red[1][3][row];
          float mean = S*(1.0f/DD);
          float var  = S2*(1.0f/DD) - mean*mean;
          float rstd = rsqrtf(var + 1e-5f);
          #pragma unroll
          for(int ni=0;ni<NT;ni++){
            float v = acc[mi][ni][r]+bv[ni];
            v = fmaxf((v-mean)*rstd*gcol[ni] + bcol[ni], 0.f);
            if constexpr (EP==EP_AT){
              float y2v = b2f(aux1[(size_t)gr*DD + colg[ni]]);
              float g0v = b2f(aux2[(size_t)gr*DD + colg[ni]]);
              float x2v = fmaxf(p4c[ni]*y2v + p5c[ni], 0.f) + g0v;
              v = 0.8f*x2v + 0.2f*v;
            }
            outb[(size_t)gr*DD + colg[ni]] = f2b(v);
          }
        }
      }
  }
}

// ---------------- launch ----------------
extern "C" void kernel_launch(void* const* d_in, const int* in_sizes, int n_in,
                              void* d_out, int out_size, void* d_ws, size_t ws_size,
                              hipStream_t stream) {
  (void)in_sizes; (void)n_in; (void)out_size; (void)ws_size;
  const float* x     = (const float*)d_in[0];
  const int*   ei    = (const int*)d_in[1];
  const float* tW0   = (const float*)d_in[2];
  const float* tb0   = (const float*)d_in[3];
  const float* tln0g = (const float*)d_in[4];
  const float* tln0b = (const float*)d_in[5];
  const float* Wq    = (const float*)d_in[6];
  const float* bq    = (const float*)d_in[7];
  const float* Wk    = (const float*)d_in[8];
  const float* bk    = (const float*)d_in[9];
  const float* Wv    = (const float*)d_in[10];
  const float* bvv   = (const float*)d_in[11];
  const float* tln1g = (const float*)d_in[12];
  const float* tln1b = (const float*)d_in[13];
  const float* gW0   = (const float*)d_in[14];
  const float* gb0   = (const float*)d_in[15];
  const float* gbn0g = (const float*)d_in[16];
  const float* gbn0b = (const float*)d_in[17];
  const float* gWc   = (const float*)d_in[18];
  const float* gbc   = (const float*)d_in[19];
  const float* gbn1g = (const float*)d_in[20];
  const float* gbn1b = (const float*)d_in[21];
  const float* Wo    = (const float*)d_in[22];
  const float* bo    = (const float*)d_in[23];

  char* ws = (char*)d_ws;
  size_t off = 0;
  auto give = [&](size_t b){ size_t o = off; off += (b + 511) & ~(size_t)511; return o; };
  const size_t NB = (size_t)NN*DD*2;   // 51.2 MB bf16 buffer
  size_t o_b0=give(NB), o_b1=give(NB), o_b2=give(NB), o_b3=give(NB), o_b4=give(NB);
  size_t o_csr = give((size_t)NEG*4);
  size_t o_rowstart = give((NN+1)*4);
  size_t o_cursor   = give(NN*4);
  size_t o_dsq      = give(NN*4);
  size_t o_part     = give(512*4);
  size_t o_wt0=give(DD*DD*2), o_wq=give(DD*DD*2), o_wk=give(DD*DD*2), o_wv=give(DD*DD*2);
  size_t o_wg0=give(DD*DD*2), o_wgc=give(DD*DD*2), o_wo=give(DD*DOUT*2);
  size_t o_kvsT=give(DD*DD*2);
  size_t o_sc0=give(DD*4), o_sh0=give(DD*4), o_sc1=give(DD*4), o_sh1=give(DD*4);
  // zero region (contiguous): zeropad, deg, kvs, ksum, vsum, cs0, cq0, cs1, cq1
  size_t o_zero = off;
  size_t o_zpad = give(1024);
  size_t o_deg = give(NN*4);
  size_t o_kvs = give(DD*DD*4);
  size_t o_ksum=give(DD*4), o_vsum=give(DD*4);
  size_t o_cs0=give(DD*4), o_cq0=give(DD*4), o_cs1=give(DD*4), o_cq1=give(DD*4);
  size_t zero_len = off - o_zero;

  u16* B0=(u16*)(ws+o_b0); u16* B1=(u16*)(ws+o_b1); u16* B2=(u16*)(ws+o_b2);
  u16* B3=(u16*)(ws+o_b3); u16* B4=(u16*)(ws+o_b4);
  int* csr=(int*)(ws+o_csr); int* rowstart=(int*)(ws+o_rowstart); int* cursor=(int*)(ws+o_cursor);
  float* dsq=(float*)(ws+o_dsq); int* part=(int*)(ws+o_part);
  u16* wt0=(u16*)(ws+o_wt0); u16* wq=(u16*)(ws+o_wq); u16* wk=(u16*)(ws+o_wk); u16* wv=(u16*)(ws+o_wv);
  u16* wg0=(u16*)(ws+o_wg0); u16* wgc=(u16*)(ws+o_wgc); u16* wo=(u16*)(ws+o_wo);
  u16* kvsT=(u16*)(ws+o_kvsT);
  float* sc0=(float*)(ws+o_sc0); float* sh0=(float*)(ws+o_sh0);
  float* sc1=(float*)(ws+o_sc1); float* sh1=(float*)(ws+o_sh1);
  u16* zp=(u16*)(ws+o_zpad);
  int* deg=(int*)(ws+o_deg); float* kvs=(float*)(ws+o_kvs);
  float* ksum=(float*)(ws+o_ksum); float* vsum=(float*)(ws+o_vsum);
  float* cs0=(float*)(ws+o_cs0); float* cq0=(float*)(ws+o_cq0);
  float* cs1=(float*)(ws+o_cs1); float* cq1=(float*)(ws+o_cq1);

  hipMemsetAsync(ws + o_zero, 0, zero_len, stream);

  // weights -> transposed bf16
  k_wtrans<<<256,256,0,stream>>>(tW0, wt0, 256);
  k_wtrans<<<256,256,0,stream>>>(Wq,  wq,  256);
  k_wtrans<<<256,256,0,stream>>>(Wk,  wk,  256);
  k_wtrans<<<256,256,0,stream>>>(Wv,  wv,  256);
  k_wtrans<<<256,256,0,stream>>>(gW0, wg0, 256);
  k_wtrans<<<256,256,0,stream>>>(gWc, wgc, 256);
  k_wtrans<<<128,256,0,stream>>>(Wo,  wo,  128);

  // graph CSR
  k_deg<<<6250,256,0,stream>>>(ei, deg);
  k_scan_a<<<391,256,0,stream>>>(deg, part);
  k_scan_b<<<1,512,0,stream>>>(part);
  k_scan_c<<<391,256,0,stream>>>(deg, part, rowstart, cursor, dsq);
  k_csr<<<6250,256,0,stream>>>(ei, cursor, csr);

  // x -> bf16 (into B2; B2 is reused for q later)
  k_cvt<<<12500,256,0,stream>>>(x, B2);

  const int MG = 1563;  // ceil(100000/64)
  #define GEMM_ARGS(A_,BT_,bias_,outb_,outf_,P0,P1,P2,P3,P4,P5,AX0,AX1,AX2,S0,S1,ks,kl,as_,bs_,ml) \
      (A_),(BT_),(bias_),(outb_),(outf_),(P0),(P1),(P2),(P3),(P4),(P5),(AX0),(AX1),(AX2),(S0),(S1),zp,(ks),(kl),(as_),(bs_),(ml)

  // h = relu(LN(x@tW0+tb0))
  k_gemm<EP_LN,256><<<dim3(MG,1),256,0,stream>>>(GEMM_ARGS(B2,wt0,tb0,B0,nullptr,
      tln0g,tln0b,nullptr,nullptr,nullptr,nullptr,nullptr,nullptr,nullptr,nullptr,nullptr,
      8,256,256,256,NN));
  // yg = x@gW0+gb0 (+colstats)
  k_gemm<EP_CS,256><<<dim3(MG,1),256,0,stream>>>(GEMM_ARGS(B2,wg0,gb0,B1,nullptr,
      nullptr,nullptr,nullptr,nullptr,nullptr,nullptr,nullptr,nullptr,nullptr,cs0,cq0,
      8,256,256,256,NN));
  // q = rownorm(h@Wq+bq)  (xb in B2 now dead)
  k_gemm<EP_QN,256><<<dim3(MG,1),256,0,stream>>>(GEMM_ARGS(B0,wq,bq,B2,nullptr,
      nullptr,nullptr,nullptr,nullptr,nullptr,nullptr,nullptr,nullptr,nullptr,nullptr,nullptr,
      8,256,256,256,NN));
  // kT = rownorm(h@Wk+bk)^T  (+ksum)
  k_gemm<EP_KT,256><<<dim3(MG,1),256,0,stream>>>(GEMM_ARGS(B0,wk,bk,B3,nullptr,
      nullptr,nullptr,nullptr,nullptr,nullptr,nullptr,nullptr,nullptr,nullptr,ksum,nullptr,
      8,256,256,256,NN));
  // vT = (h@Wv+bv)^T  (+vsum)
  k_gemm<EP_VT,256><<<dim3(MG,1),256,0,stream>>>(GEMM_ARGS(B0,wv,bvv,B4,nullptr,
      nullptr,nullptr,nullptr,nullptr,nullptr,nullptr,nullptr,nullptr,nullptr,vsum,nullptr,
      8,256,256,256,NN));
  // kvs = k^T @ v  (split-K atomic fp32); 98*32*32 = 100352 >= 100000
  k_gemm<EP_KV,256><<<dim3(4,98),256,0,stream>>>(GEMM_ARGS(B3,B4,nullptr,nullptr,kvs,
      nullptr,nullptr,nullptr,nullptr,nullptr,nullptr,nullptr,nullptr,nullptr,nullptr,nullptr,
      32,NN,NN,NN,256));
  k_wtrans<<<256,256,0,stream>>>(kvs, kvsT, 256);
  // BN0 -> g0 (B3 reuse: kT consumed by kvs)
  k_bnprep<<<1,256,0,stream>>>(cs0, cq0, gbn0g, gbn0b, sc0, sh0);
  k_bnrelu<<<12500,256,0,stream>>>(B1, sc0, sh0, B3);
  // agg (B1 reuse: yg dead)
  k_gather<<<12500,256,0,stream>>>(B3, rowstart, csr, dsq, B1);
  // y2 = agg@gWc+gbc (+colstats) (B4 reuse: vT dead)
  k_gemm<EP_CS,256><<<dim3(MG,1),256,0,stream>>>(GEMM_ARGS(B1,wgc,gbc,B4,nullptr,
      nullptr,nullptr,nullptr,nullptr,nullptr,nullptr,nullptr,nullptr,nullptr,cs1,cq1,
      8,256,256,256,NN));
  k_bnprep<<<1,256,0,stream>>>(cs1, cq1, gbn1g, gbn1b, sc1, sh1);
  // z = 0.8*(relu(bn1(y2))+g0) + 0.2*relu(LN((num/den + h)/2))   (B1 reuse: agg dead)
  k_gemm<EP_AT,256><<<dim3(MG,1),256,0,stream>>>(GEMM_ARGS(B2,kvsT,nullptr,B1,nullptr,
      tln1g,tln1b,ksum,vsum,sc1,sh1,B0,B4,B3,nullptr,nullptr,
      8,256,256,256,NN));
  // out = z @ Wo + bo  (fp32)
  k_gemm<EP_PL,128><<<dim3(MG,1),256,0,stream>>>(GEMM_ARGS(B1,wo,bo,nullptr,(float*)d_out,
      nullptr,nullptr,nullptr,nullptr,nullptr,nullptr,nullptr,nullptr,nullptr,nullptr,nullptr,
      8,256,256,256,NN));
  #undef GEMM_ARGS
}

// Round 3
// 1200.580 us; speedup vs baseline: 1.0578x; 1.0578x over previous
//
#include <hip/hip_runtime.h>
#include <hip/hip_bf16.h>

#define NN 100000
#define NNP 100352   // NN padded to multiple of 64 AND 64-elem (128B) alignment for transposed rows
#define NEG 1600000
#define DD 256
#define DOUT 128

typedef unsigned short u16;
typedef unsigned int u32;
typedef __attribute__((ext_vector_type(8))) __bf16 bf16x8;
typedef __attribute__((ext_vector_type(4))) float f32x4;

__device__ __forceinline__ float b2f(u16 b){ u32 u=((u32)b)<<16; float f; __builtin_memcpy(&f,&u,4); return f; }
__device__ __forceinline__ u16 f2b(float f){ u32 u; __builtin_memcpy(&u,&f,4); u32 r=(u + 0x7FFFu + ((u>>16)&1u))>>16; return (u16)r; }
__device__ __forceinline__ u32 pack2(float a, float b){ return (u32)f2b(a) | ((u32)f2b(b)<<16); }

// async 16B global -> LDS (lane i lands at ldsbase + i*16); global src per-lane arbitrary
__device__ __forceinline__ void cp16(const u16* g, u16* l){
  __builtin_amdgcn_global_load_lds((const __attribute__((address_space(1))) u16*)g,
                                   (__attribute__((address_space(3))) u16*)l, 16, 0, 0);
}

// ---------------- x fp32 -> bf16 ----------------
__global__ void k_cvt(const float* __restrict__ x, u16* __restrict__ xb){
  size_t i = (size_t)(blockIdx.x*256 + threadIdx.x)*8;
  if(i >= (size_t)NN*DD) return;
  float4 a = *(const float4*)&x[i];
  float4 b = *(const float4*)&x[i+4];
  uint4 v; v.x=pack2(a.x,a.y); v.y=pack2(a.z,a.w); v.z=pack2(b.x,b.y); v.w=pack2(b.z,b.w);
  *(uint4*)&xb[i] = v;
}

// ---------------- weight transpose (fp32 [256][ncols] -> bf16 [ncols][256]) ----------------
__global__ void k_wtrans(const float* __restrict__ W, u16* __restrict__ WT, int ncols){
  int n = blockIdx.x; int k = threadIdx.x;
  WT[n*DD + k] = f2b(W[k*ncols + n]);
}

// ---------------- graph prep ----------------
__global__ void k_deg(const int* __restrict__ ei, int* __restrict__ deg){
  int e = blockIdx.x*256 + threadIdx.x;
  if(e < NEG) atomicAdd(&deg[ei[NEG + e]], 1);
}

__global__ void k_scan_a(const int* __restrict__ deg, int* __restrict__ part){
  __shared__ int s[256];
  int i = blockIdx.x*256 + threadIdx.x;
  int v = (i < NN) ? deg[i] : 0;
  s[threadIdx.x] = v; __syncthreads();
  for(int o=128;o>0;o>>=1){ if(threadIdx.x<o) s[threadIdx.x]+=s[threadIdx.x+o]; __syncthreads(); }
  if(threadIdx.x==0) part[blockIdx.x]=s[0];
}

__global__ void k_scan_b(int* __restrict__ part){
  __shared__ int s[512];
  int tx = threadIdx.x;
  int v = (tx < 391) ? part[tx] : 0;
  s[tx] = v; __syncthreads();
  for(int o=1;o<512;o<<=1){ int t=(tx>=o)?s[tx-o]:0; __syncthreads(); s[tx]+=t; __syncthreads(); }
  if(tx < 391) part[tx] = s[tx]-v;  // exclusive
}

__global__ void k_scan_c(const int* __restrict__ deg, const int* __restrict__ part,
                         int* __restrict__ rowstart, int* __restrict__ cursor, float* __restrict__ dsq){
  __shared__ int s[256];
  int tx = threadIdx.x;
  int i = blockIdx.x*256 + tx;
  int v = (i < NN) ? deg[i] : 0;
  s[tx]=v; __syncthreads();
  for(int o=1;o<256;o<<=1){ int t=(tx>=o)?s[tx-o]:0; __syncthreads(); s[tx]+=t; __syncthreads(); }
  int incl = s[tx];
  int base = part[blockIdx.x];
  if(i < NN){
    int excl = base + incl - v;
    rowstart[i]=excl; cursor[i]=excl;
    dsq[i] = (v>0) ? rsqrtf((float)v) : 0.f;
    if(i == NN-1) rowstart[NN] = base + incl;
  }
}

__global__ void k_csr(const int* __restrict__ ei, int* __restrict__ cursor, int* __restrict__ csr_row){
  int e = blockIdx.x*256 + threadIdx.x;
  if(e < NEG){
    int r = ei[e], c = ei[NEG + e];
    int p = atomicAdd(&cursor[c], 1);
    csr_row[p] = r;
  }
}

// ---------------- BN helpers ----------------
__global__ void k_bnprep(const float* __restrict__ cs, const float* __restrict__ cq,
                         const float* __restrict__ g, const float* __restrict__ b,
                         float* __restrict__ scale, float* __restrict__ shift){
  int c = threadIdx.x;
  float m = cs[c] * (1.0f/NN);
  float var = cq[c] * (1.0f/NN) - m*m;
  float rs = rsqrtf(var + 1e-5f);
  float sc = g[c]*rs;
  scale[c] = sc; shift[c] = b[c] - m*sc;
}

__global__ void k_bnrelu(const u16* __restrict__ yg, const float* __restrict__ scale,
                         const float* __restrict__ shift, u16* __restrict__ g0){
  long long i = (long long)(blockIdx.x*256 + threadIdx.x) * 8;
  if(i >= (long long)NN*DD) return;
  int c0 = (int)(i & 255);
  uint4 v = *(const uint4*)&yg[i];
  const u16* p = (const u16*)&v;
  u32 w[4];
  #pragma unroll
  for(int j=0;j<4;j++){
    float a = fmaxf(b2f(p[2*j  ])*scale[c0+2*j  ]+shift[c0+2*j  ], 0.f);
    float b_ = fmaxf(b2f(p[2*j+1])*scale[c0+2*j+1]+shift[c0+2*j+1], 0.f);
    w[j] = pack2(a,b_);
  }
  uint4 sv; sv.x=w[0]; sv.y=w[1]; sv.z=w[2]; sv.w=w[3];
  *(uint4*)&g0[i] = sv;
}

// ---------------- CSR gather: agg[i] = sum_e dsq[i]*dsq[row]*g0[row] ----------------
__global__ __launch_bounds__(256) void k_gather(const u16* __restrict__ g0, const int* __restrict__ rowstart,
                                                const int* __restrict__ csr_row, const float* __restrict__ dsq,
                                                u16* __restrict__ agg){
  int node = blockIdx.x*8 + (threadIdx.x>>5);
  int lane = threadIdx.x & 31;
  if(node >= NN) return;
  int s = rowstart[node], e = rowstart[node+1];
  float di = dsq[node];
  int d0 = lane*8;
  float acc[8] = {0,0,0,0,0,0,0,0};
  int j = s;
  for(; j+1 < e; j += 2){
    int r0 = csr_row[j], r1 = csr_row[j+1];
    float w0 = di*dsq[r0], w1 = di*dsq[r1];
    uint4 a = *(const uint4*)&g0[(size_t)r0*DD + d0];
    uint4 b = *(const uint4*)&g0[(size_t)r1*DD + d0];
    const u16* pa = (const u16*)&a; const u16* pb = (const u16*)&b;
    #pragma unroll
    for(int t=0;t<8;t++){ acc[t] += w0*b2f(pa[t]); acc[t] += w1*b2f(pb[t]); }
  }
  if(j < e){
    int r0 = csr_row[j]; float w0 = di*dsq[r0];
    uint4 a = *(const uint4*)&g0[(size_t)r0*DD + d0];
    const u16* pa = (const u16*)&a;
    #pragma unroll
    for(int t=0;t<8;t++) acc[t] += w0*b2f(pa[t]);
  }
  u32 w[4];
  #pragma unroll
  for(int t=0;t<4;t++) w[t] = pack2(acc[2*t], acc[2*t+1]);
  uint4 sv; sv.x=w[0]; sv.y=w[1]; sv.z=w[2]; sv.w=w[3];
  *(uint4*)&agg[(size_t)node*DD + d0] = sv;
}

// ---------------- kvs split-K partial reduce: kvs[m][d] = sum_y part[y][m][d] ----------------
#define KVY 98
__global__ void k_kvsred(const u16* __restrict__ part, float* __restrict__ kvs){
  int m = blockIdx.x, d = threadIdx.x;
  float s = 0.f;
  for(int y=0;y<KVY;y++) s += b2f(part[(size_t)y*65536 + m*256 + d]);
  kvs[m*256 + d] = s;
}

// ---------------- B-resident-in-LDS MFMA GEMM ----------------
// Geometry: block = 256 thr = 4 waves; wave w owns rows m0+w*16..+16, ALL NCOLS cols.
// B staged fully in LDS in kSteps slabs of 128 k (xor-swizzled 16B chunks).
// A fragments loaded directly global->VGPR per lane.
// EP: 0=LN+relu(h) 1=row-L2-norm(q) 2=rownorm+transp+colsum(kT) 3=transp+colsum(vT)
//     4=store+colstats 5=attention+LN+relu+final-combine->z 6=plain fp32 out 7=split-K partial (kvs)
enum { EP_LN=0, EP_QN=1, EP_KT=2, EP_VT=3, EP_CS=4, EP_AT=5, EP_PL=6, EP_KV=7 };

template<int EP, int NCOLS>
__global__ __launch_bounds__(256)
void k_gemm(const u16* __restrict__ A, const u16* __restrict__ BT,
            const float* __restrict__ bias,
            u16* __restrict__ outb, float* __restrict__ outf,
            const float* __restrict__ p0, const float* __restrict__ p1,
            const float* __restrict__ p2, const float* __restrict__ p3,
            const float* __restrict__ p4, const float* __restrict__ p5,
            const u16* __restrict__ aux0, const u16* __restrict__ aux1, const u16* __restrict__ aux2,
            float* __restrict__ st0, float* __restrict__ st1,
            int kSteps, long long Astride, long long Bstride, int Mlim)
{
  constexpr int NT = NCOLS/16;     // col-tiles per wave (each wave covers ALL cols)
  extern __shared__ __align__(16) u16 lds[];   // NCOLS*128 u16 per slab
  const int tid=threadIdx.x, wave=tid>>6, lane=tid&63, quad=lane>>4, l15=lane&15;
  const int m0 = blockIdx.x*64;
  const int kOff = blockIdx.y * (kSteps*128);
  const int rowA = m0 + wave*16 + l15;               // A-fragment row of this lane
  const u16* aBase = A + (long long)rowA*Astride + quad*8;

  f32x4 acc[NT];
  #pragma unroll
  for(int ni=0;ni<NT;ni++){ acc[ni][0]=0.f; acc[ni][1]=0.f; acc[ni][2]=0.f; acc[ni][3]=0.f; }
  float dot = 0.f;

  // stage one 128-k slab of B^T into LDS: chunk c -> (col=c>>4, kchunk=(c&15)^(col&7))
  // each wave-instruction reads 1KB contiguous global (8 dense lines)
  auto stage = [&](int kb){
    #pragma unroll
    for(int i=0;i<NT;i++){
      int c = i*256 + tid;
      int col = c>>4, kc = c&15;
      cp16(BT + (long long)col*Bstride + kb + ((kc ^ (col&7))<<3), &lds[c*8]);
    }
  };

  stage(kOff);
  for(int st=0; st<kSteps; st++){
    const int kb = kOff + st*128;
    // A fragments: 4 independent direct global loads (issued before barrier wait resolves)
    uint4 a4[4];
    #pragma unroll
    for(int ks=0;ks<4;ks++) a4[ks] = *(const uint4*)(aBase + kb + ks*32);
    __syncthreads();   // slab visible
    if constexpr (EP==EP_AT){
      #pragma unroll
      for(int ks=0;ks<4;ks++){
        const u16* ap=(const u16*)&a4[ks];
        #pragma unroll
        for(int j=0;j<8;j++) dot += b2f(ap[j]) * p2[kb + ks*32 + quad*8 + j];
      }
    }
    #pragma unroll
    for(int ks=0;ks<4;ks++){
      const int x = ks*4 + quad;
      #pragma unroll
      for(int ni=0;ni<NT;ni++){
        const int col = ni*16 + l15;
        uint4 b = *(const uint4*)&lds[((col<<4) + (x ^ (col&7)))*8];
        acc[ni] = __builtin_amdgcn_mfma_f32_16x16x32_bf16(
            __builtin_bit_cast(bf16x8, a4[ks]),
            __builtin_bit_cast(bf16x8, b),
            acc[ni], 0,0,0);
      }
    }
    if(st+1<kSteps){ __syncthreads(); stage(kOff + (st+1)*128); }
  }

  int colg[NT]; float bv[NT];
  #pragma unroll
  for(int ni=0;ni<NT;ni++){ colg[ni] = ni*16 + l15; bv[ni] = bias ? bias[colg[ni]] : 0.f; }

  if constexpr (EP==EP_KV){
    #pragma unroll
    for(int r=0;r<4;r++){
      int gr = m0 + wave*16 + quad*4 + r;
      #pragma unroll
      for(int ni=0;ni<NT;ni++)
        outb[(size_t)blockIdx.y*65536 + (size_t)gr*256 + colg[ni]] = f2b(acc[ni][r]);
    }
    return;
  }
  if constexpr (EP==EP_PL){
    #pragma unroll
    for(int r=0;r<4;r++){
      int gr = m0 + wave*16 + quad*4 + r;
      if(gr<Mlim){
        #pragma unroll
        for(int ni=0;ni<NT;ni++) outf[(size_t)gr*NCOLS + colg[ni]] = acc[ni][r] + bv[ni];
      }
    }
    return;
  }
  if constexpr (EP==EP_LN){
    #pragma unroll
    for(int r=0;r<4;r++){
      float v[NT]; float s=0.f, s2=0.f;
      #pragma unroll
      for(int ni=0;ni<NT;ni++){ v[ni]=acc[ni][r]+bv[ni]; s+=v[ni]; s2+=v[ni]*v[ni]; }
      #pragma unroll
      for(int o=1;o<16;o<<=1){ s += __shfl_xor(s,o); s2 += __shfl_xor(s2,o); }
      int gr = m0 + wave*16 + quad*4 + r;
      if(gr<Mlim){
        float mean = s*(1.0f/DD);
        float var  = s2*(1.0f/DD) - mean*mean;
        float rstd = rsqrtf(var + 1e-5f);
        #pragma unroll
        for(int ni=0;ni<NT;ni++)
          outb[(size_t)gr*DD + colg[ni]] = f2b(fmaxf((v[ni]-mean)*rstd*p0[colg[ni]] + p1[colg[ni]], 0.f));
      }
    }
    return;
  }
  if constexpr (EP==EP_QN){
    #pragma unroll
    for(int r=0;r<4;r++){
      float v[NT]; float s2=0.f;
      #pragma unroll
      for(int ni=0;ni<NT;ni++){ v[ni]=acc[ni][r]+bv[ni]; s2+=v[ni]*v[ni]; }
      #pragma unroll
      for(int o=1;o<16;o<<=1) s2 += __shfl_xor(s2,o);
      int gr = m0 + wave*16 + quad*4 + r;
      if(gr<Mlim){
        float rsr = rsqrtf(s2);
        #pragma unroll
        for(int ni=0;ni<NT;ni++) outb[(size_t)gr*DD + colg[ni]] = f2b(v[ni]*rsr);
      }
    }
    return;
  }
  if constexpr (EP==EP_CS){
    __syncthreads();
    float* red0 = (float*)lds; float* red1 = red0 + 256;
    red0[tid]=0.f; red1[tid]=0.f;
    __syncthreads();
    #pragma unroll
    for(int ni=0;ni<NT;ni++){
      float cs=0.f, cq=0.f;
      #pragma unroll
      for(int r=0;r<4;r++){
        int gr = m0 + wave*16 + quad*4 + r;
        float v = (gr<Mlim) ? acc[ni][r]+bv[ni] : 0.f;
        if(gr<Mlim) outb[(size_t)gr*DD + colg[ni]] = f2b(v);
        cs+=v; cq+=v*v;
      }
      cs += __shfl_xor(cs,16); cs += __shfl_xor(cs,32);
      cq += __shfl_xor(cq,16); cq += __shfl_xor(cq,32);
      if(lane<16){ atomicAdd(&red0[colg[ni]], cs); atomicAdd(&red1[colg[ni]], cq); }
    }
    __syncthreads();
    atomicAdd(&st0[tid], red0[tid]);
    atomicAdd(&st1[tid], red1[tid]);
    return;
  }
  if constexpr (EP==EP_KT || EP==EP_VT){
    float rsr4[4];
    #pragma unroll
    for(int r=0;r<4;r++){
      if constexpr (EP==EP_KT){
        float s2=0.f;
        #pragma unroll
        for(int ni=0;ni<NT;ni++){ float v=acc[ni][r]+bv[ni]; s2+=v*v; }
        #pragma unroll
        for(int o=1;o<16;o<<=1) s2 += __shfl_xor(s2,o);
        rsr4[r] = rsqrtf(s2);
      } else rsr4[r] = 1.f;
    }
    __syncthreads();            // done reading Bs
    float* red0 = (float*)lds;
    red0[tid]=0.f;
    __syncthreads();
    float vv[NT][4];
    #pragma unroll
    for(int ni=0;ni<NT;ni++){
      float cs=0.f;
      #pragma unroll
      for(int r=0;r<4;r++){
        int gr = m0 + wave*16 + quad*4 + r;
        float v = (gr<Mlim) ? (acc[ni][r]+bv[ni])*rsr4[r] : 0.f;   // zero tail rows -> clean NNP pad
        vv[ni][r]=v; cs+=v;
      }
      cs += __shfl_xor(cs,16); cs += __shfl_xor(cs,32);
      if(lane<16) atomicAdd(&red0[colg[ni]], cs);
    }
    __syncthreads();
    atomicAdd(&st0[tid], red0[tid]);
    __syncthreads();            // red consumed; reuse lds as swizzled transpose buffer
    #pragma unroll
    for(int r=0;r<4;r++){
      int rowL = wave*16 + quad*4 + r;
      int xo = (rowL&7)<<2;
      #pragma unroll
      for(int ni=0;ni<NT;ni++) lds[rowL*256 + (colg[ni]^xo)] = f2b(vv[ni][r]);
    }
    __syncthreads();
    #pragma unroll
    for(int i=0;i<8;i++){
      int c = i*256 + tid;
      int d = c>>3, ns = c&7;
      u16 e[8];
      #pragma unroll
      for(int k=0;k<8;k++){ int nl = ns*8+k; e[k] = lds[nl*256 + (d ^ ((nl&7)<<2))]; }
      uint4 pk; pk.x=(u32)e[0]|((u32)e[1]<<16); pk.y=(u32)e[2]|((u32)e[3]<<16);
      pk.z=(u32)e[4]|((u32)e[5]<<16); pk.w=(u32)e[6]|((u32)e[7]<<16);
      *(uint4*)&outb[(size_t)d*NNP + m0 + ns*8] = pk;
    }
    return;
  }
  if constexpr (EP==EP_AT){
    dot += __shfl_xor(dot,16); dot += __shfl_xor(dot,32);   // full q.ksum for row (l15) of this wave
    float vsc[NT], gcol[NT], bcol[NT], p4c[NT], p5c[NT];
    #pragma unroll
    for(int ni=0;ni<NT;ni++){
      vsc[ni]=p3[colg[ni]]; gcol[ni]=p0[colg[ni]]; bcol[ni]=p1[colg[ni]];
      p4c[ni]=p4[colg[ni]]; p5c[ni]=p5[colg[ni]];
    }
    #pragma unroll
    for(int r=0;r<4;r++){
      int gr = m0 + wave*16 + quad*4 + r;
      bool ok = gr<Mlim;
      float den = __shfl(dot, (lane&48)|(quad*4+r)) + 200000.0f;   // + 2*nf
      float t[NT]; float s=0.f, s2=0.f;
      #pragma unroll
      for(int ni=0;ni<NT;ni++){
        float num = acc[ni][r] + 100000.0f*vsc[ni];
        float hv = ok ? b2f(aux0[(size_t)gr*DD + colg[ni]]) : 0.f;
        t[ni] = (num/den + hv)*0.5f;
        s+=t[ni]; s2+=t[ni]*t[ni];
      }
      #pragma unroll
      for(int o=1;o<16;o<<=1){ s += __shfl_xor(s,o); s2 += __shfl_xor(s2,o); }
      if(ok){
        float mean = s*(1.0f/DD);
        float var  = s2*(1.0f/DD) - mean*mean;
        float rstd = rsqrtf(var + 1e-5f);
        #pragma unroll
        for(int ni=0;ni<NT;ni++){
          float x1v = fmaxf((t[ni]-mean)*rstd*gcol[ni] + bcol[ni], 0.f);
          float y2v = b2f(aux1[(size_t)gr*DD + colg[ni]]);
          float g0v = b2f(aux2[(size_t)gr*DD + colg[ni]]);
          float x2v = fmaxf(p4c[ni]*y2v + p5c[ni], 0.f) + g0v;
          outb[(size_t)gr*DD + colg[ni]] = f2b(0.8f*x2v + 0.2f*x1v);
        }
      }
    }
  }
}

// ---------------- launch ----------------
extern "C" void kernel_launch(void* const* d_in, const int* in_sizes, int n_in,
                              void* d_out, int out_size, void* d_ws, size_t ws_size,
                              hipStream_t stream) {
  (void)in_sizes; (void)n_in; (void)out_size; (void)ws_size;
  const float* x     = (const float*)d_in[0];
  const int*   ei    = (const int*)d_in[1];
  const float* tW0   = (const float*)d_in[2];
  const float* tb0   = (const float*)d_in[3];
  const float* tln0g = (const float*)d_in[4];
  const float* tln0b = (const float*)d_in[5];
  const float* Wq    = (const float*)d_in[6];
  const float* bq    = (const float*)d_in[7];
  const float* Wk    = (const float*)d_in[8];
  const float* bk    = (const float*)d_in[9];
  const float* Wv    = (const float*)d_in[10];
  const float* bvv   = (const float*)d_in[11];
  const float* tln1g = (const float*)d_in[12];
  const float* tln1b = (const float*)d_in[13];
  const float* gW0   = (const float*)d_in[14];
  const float* gb0   = (const float*)d_in[15];
  const float* gbn0g = (const float*)d_in[16];
  const float* gbn0b = (const float*)d_in[17];
  const float* gWc   = (const float*)d_in[18];
  const float* gbc   = (const float*)d_in[19];
  const float* gbn1g = (const float*)d_in[20];
  const float* gbn1b = (const float*)d_in[21];
  const float* Wo    = (const float*)d_in[22];
  const float* bo    = (const float*)d_in[23];

  char* ws = (char*)d_ws;
  size_t off = 0;
  auto give = [&](size_t b){ size_t o = off; off += (b + 511) & ~(size_t)511; return o; };
  const size_t NB = (size_t)NNP*DD*2;         // padded row-major bf16 buffer
  const size_t TB = (size_t)256*NNP*2;        // transposed [256][NNP] bf16 buffer
  size_t o_b0=give(NB), o_b1=give(NB), o_b2=give(NB);
  size_t o_kt=give(TB), o_vt=give(TB);
  size_t o_kvp = give((size_t)KVY*65536*2);   // kvs bf16 partials
  size_t o_csr = give((size_t)NEG*4);
  size_t o_rowstart = give((NN+1)*4);
  size_t o_cursor   = give(NN*4);
  size_t o_dsq      = give(NN*4);
  size_t o_part     = give(512*4);
  size_t o_wt0=give(DD*DD*2), o_wq=give(DD*DD*2), o_wk=give(DD*DD*2), o_wv=give(DD*DD*2);
  size_t o_wg0=give(DD*DD*2), o_wgc=give(DD*DD*2), o_wo=give(DD*DOUT*2);
  size_t o_kvs=give(DD*DD*4), o_kvsT=give(DD*DD*2);
  size_t o_sc0=give(DD*4), o_sh0=give(DD*4), o_sc1=give(DD*4), o_sh1=give(DD*4);
  // zero region: deg + stats
  size_t o_zero = off;
  size_t o_deg = give(NN*4);
  size_t o_ksum=give(DD*4), o_vsum=give(DD*4);
  size_t o_cs0=give(DD*4), o_cq0=give(DD*4), o_cs1=give(DD*4), o_cq1=give(DD*4);
  size_t zero_len = off - o_zero;

  u16* B0=(u16*)(ws+o_b0); u16* B1=(u16*)(ws+o_b1); u16* B2=(u16*)(ws+o_b2);
  u16* KT=(u16*)(ws+o_kt); u16* VT=(u16*)(ws+o_vt);
  u16* KVP=(u16*)(ws+o_kvp);
  int* csr=(int*)(ws+o_csr); int* rowstart=(int*)(ws+o_rowstart); int* cursor=(int*)(ws+o_cursor);
  float* dsq=(float*)(ws+o_dsq); int* partb=(int*)(ws+o_part);
  u16* wt0=(u16*)(ws+o_wt0); u16* wq=(u16*)(ws+o_wq); u16* wk=(u16*)(ws+o_wk); u16* wv=(u16*)(ws+o_wv);
  u16* wg0=(u16*)(ws+o_wg0); u16* wgc=(u16*)(ws+o_wgc); u16* wo=(u16*)(ws+o_wo);
  float* kvs=(float*)(ws+o_kvs); u16* kvsT=(u16*)(ws+o_kvsT);
  float* sc0=(float*)(ws+o_sc0); float* sh0=(float*)(ws+o_sh0);
  float* sc1=(float*)(ws+o_sc1); float* sh1=(float*)(ws+o_sh1);
  int* deg=(int*)(ws+o_deg);
  float* ksum=(float*)(ws+o_ksum); float* vsum=(float*)(ws+o_vsum);
  float* cs0=(float*)(ws+o_cs0); float* cq0=(float*)(ws+o_cq0);
  float* cs1=(float*)(ws+o_cs1); float* cq1=(float*)(ws+o_cq1);

  // opt in to 64KB dynamic LDS (defensive; ignore errors)
  static bool attr_done = false;
  if(!attr_done){
    hipFuncSetAttribute((const void*)k_gemm<EP_LN,256>, hipFuncAttributeMaxDynamicSharedMemorySize, 65536);
    hipFuncSetAttribute((const void*)k_gemm<EP_CS,256>, hipFuncAttributeMaxDynamicSharedMemorySize, 65536);
    hipFuncSetAttribute((const void*)k_gemm<EP_QN,256>, hipFuncAttributeMaxDynamicSharedMemorySize, 65536);
    hipFuncSetAttribute((const void*)k_gemm<EP_KT,256>, hipFuncAttributeMaxDynamicSharedMemorySize, 65536);
    hipFuncSetAttribute((const void*)k_gemm<EP_VT,256>, hipFuncAttributeMaxDynamicSharedMemorySize, 65536);
    hipFuncSetAttribute((const void*)k_gemm<EP_KV,256>, hipFuncAttributeMaxDynamicSharedMemorySize, 65536);
    hipFuncSetAttribute((const void*)k_gemm<EP_AT,256>, hipFuncAttributeMaxDynamicSharedMemorySize, 65536);
    hipFuncSetAttribute((const void*)k_gemm<EP_PL,128>, hipFuncAttributeMaxDynamicSharedMemorySize, 65536);
    attr_done = true;
  }

  hipMemsetAsync(ws + o_zero, 0, zero_len, stream);

  // weights -> transposed bf16
  k_wtrans<<<256,256,0,stream>>>(tW0, wt0, 256);
  k_wtrans<<<256,256,0,stream>>>(Wq,  wq,  256);
  k_wtrans<<<256,256,0,stream>>>(Wk,  wk,  256);
  k_wtrans<<<256,256,0,stream>>>(Wv,  wv,  256);
  k_wtrans<<<256,256,0,stream>>>(gW0, wg0, 256);
  k_wtrans<<<256,256,0,stream>>>(gWc, wgc, 256);
  k_wtrans<<<128,256,0,stream>>>(Wo,  wo,  128);

  // graph CSR
  k_deg<<<6250,256,0,stream>>>(ei, deg);
  k_scan_a<<<391,256,0,stream>>>(deg, partb);
  k_scan_b<<<1,512,0,stream>>>(partb);
  k_scan_c<<<391,256,0,stream>>>(deg, partb, rowstart, cursor, dsq);
  k_csr<<<6250,256,0,stream>>>(ei, cursor, csr);

  // x -> bf16 into B2
  k_cvt<<<12500,256,0,stream>>>(x, B2);

  const int MG = NNP/64;   // 1568
  const u16* Z16 = nullptr; (void)Z16;
  #define GA(A_,BT_,bias_,outb_,outf_,P0,P1,P2,P3,P4,P5,AX0,AX1,AX2,S0,S1,ks,as_,bs_,ml) \
      (A_),(BT_),(bias_),(outb_),(outf_),(P0),(P1),(P2),(P3),(P4),(P5),(AX0),(AX1),(AX2),(S0),(S1),(ks),(long long)(as_),(long long)(bs_),(ml)

  // h = relu(LN(x@tW0+tb0))
  k_gemm<EP_LN,256><<<dim3(MG,1),256,65536,stream>>>(GA(B2,wt0,tb0,B0,nullptr,
      tln0g,tln0b,nullptr,nullptr,nullptr,nullptr,nullptr,nullptr,nullptr,nullptr,nullptr,2,DD,DD,NN));
  // yg = x@gW0+gb0 (+colstats)
  k_gemm<EP_CS,256><<<dim3(MG,1),256,65536,stream>>>(GA(B2,wg0,gb0,B1,nullptr,
      nullptr,nullptr,nullptr,nullptr,nullptr,nullptr,nullptr,nullptr,nullptr,cs0,cq0,2,DD,DD,NN));
  // q = rownorm(h@Wq+bq) -> B2 (xb dead)
  k_gemm<EP_QN,256><<<dim3(MG,1),256,65536,stream>>>(GA(B0,wq,bq,B2,nullptr,
      nullptr,nullptr,nullptr,nullptr,nullptr,nullptr,nullptr,nullptr,nullptr,nullptr,nullptr,2,DD,DD,NN));
  // kT = rownorm(h@Wk+bk)^T  [256][NNP] (+ksum), zero tail
  k_gemm<EP_KT,256><<<dim3(MG,1),256,65536,stream>>>(GA(B0,wk,bk,KT,nullptr,
      nullptr,nullptr,nullptr,nullptr,nullptr,nullptr,nullptr,nullptr,nullptr,ksum,nullptr,2,DD,DD,NN));
  // vT = (h@Wv+bv)^T (+vsum), zero tail
  k_gemm<EP_VT,256><<<dim3(MG,1),256,65536,stream>>>(GA(B0,wv,bvv,VT,nullptr,
      nullptr,nullptr,nullptr,nullptr,nullptr,nullptr,nullptr,nullptr,nullptr,vsum,nullptr,2,DD,DD,NN));
  // kvs partials: part[y][m][d] (bf16), y covers 1024 l each
  k_gemm<EP_KV,256><<<dim3(4,KVY),256,65536,stream>>>(GA(KT,VT,nullptr,KVP,nullptr,
      nullptr,nullptr,nullptr,nullptr,nullptr,nullptr,nullptr,nullptr,nullptr,nullptr,nullptr,8,NNP,NNP,256));
  k_kvsred<<<256,256,0,stream>>>(KVP, kvs);
  k_wtrans<<<256,256,0,stream>>>(kvs, kvsT, 256);
  // BN0 -> g0 (reuse KT region; kT consumed)
  u16* G0 = KT;
  k_bnprep<<<1,256,0,stream>>>(cs0, cq0, gbn0g, gbn0b, sc0, sh0);
  k_bnrelu<<<12500,256,0,stream>>>(B1, sc0, sh0, G0);
  // agg -> B1 (yg dead)
  k_gather<<<12500,256,0,stream>>>(G0, rowstart, csr, dsq, B1);
  // y2 = agg@gWc+gbc (+colstats) -> VT region (vT consumed)
  u16* Y2 = VT;
  k_gemm<EP_CS,256><<<dim3(MG,1),256,65536,stream>>>(GA(B1,wgc,gbc,Y2,nullptr,
      nullptr,nullptr,nullptr,nullptr,nullptr,nullptr,nullptr,nullptr,nullptr,cs1,cq1,2,DD,DD,NN));
  k_bnprep<<<1,256,0,stream>>>(cs1, cq1, gbn1g, gbn1b, sc1, sh1);
  // z = 0.8*(relu(bn1(y2))+g0) + 0.2*relu(LN((num/den + h)/2)) -> B1 (agg dead)
  k_gemm<EP_AT,256><<<dim3(MG,1),256,65536,stream>>>(GA(B2,kvsT,nullptr,B1,nullptr,
      tln1g,tln1b,ksum,vsum,sc1,sh1,B0,Y2,G0,nullptr,nullptr,2,DD,DD,NN));
  // out = z @ Wo + bo (fp32)
  k_gemm<EP_PL,128><<<dim3(MG,1),256,32768,stream>>>(GA(B1,wo,bo,nullptr,(float*)d_out,
      nullptr,nullptr,nullptr,nullptr,nullptr,nullptr,nullptr,nullptr,nullptr,nullptr,nullptr,2,DD,DD,NN));
  #undef GA
}